// Round 1
// 700.114 us; speedup vs baseline: 1.2427x; 1.2427x over previous
//
#include <hip/hip_runtime.h>

#define NSP 4

typedef unsigned short u16;
typedef __bf16 v8bf __attribute__((ext_vector_type(8)));
typedef float v4f __attribute__((ext_vector_type(4)));

__device__ __forceinline__ u16 f2bf(float f){           // RNE
  union { float f; unsigned u; } v; v.f = f;
  unsigned u = v.u;
  u += 0x7fffu + ((u >> 16) & 1u);
  return (u16)(u >> 16);
}
__device__ __forceinline__ unsigned pack2bf(float x, float y){  // round-half-up, 2 bf16 in a dword
  union { float f; unsigned u; } a, b; a.f = x; b.f = y;
  unsigned ux = a.u + 0x8000u, uy = b.u + 0x8000u;
  return (uy & 0xffff0000u) | (ux >> 16);
}
__device__ __forceinline__ float fast_tanh(float x){
  // no clamp needed: exp->inf => rcp->0 => 1;  exp->0 => 1-2 = -1
  float e = __expf(2.f * x);
  return 1.f - 2.f * __builtin_amdgcn_rcpf(e + 1.f);
}

// ---------------- stable counting-sort pipeline (no atomics) ----------------
// Pass 1 (fused): per-block species histogram -> hist[s*nb + blk]; tail blocks
// convert W1/W2 to bf16 n-major transposed.
__global__ void histwconv_k(const int* __restrict__ sp, int n, int nb,
                            int* __restrict__ hist,
                            const float* __restrict__ W1, const float* __restrict__ W2,
                            u16* __restrict__ w1t, u16* __restrict__ w2t){
  int blk = blockIdx.x, tid = threadIdx.x;
  if (blk >= nb){
    int i = (blk - nb)*256 + tid;
    if (i < NSP*128*64){
      int s = i >> 13, rem = i & 8191, k = rem >> 6, nn = rem & 63;
      w1t[(s*64 + nn)*128 + k] = f2bf(W1[i]);
    }
    if (i < NSP*64*64){
      int s = i >> 12, rem = i & 4095, k = rem >> 6, nn = rem & 63;
      w2t[(s*64 + nn)*64 + k] = f2bf(W2[i]);
    }
    return;
  }
  int i = blk*256 + tid;
  int sv = (i < n) ? sp[i] : -1;
  __shared__ int wc[4][NSP];
  int lane = tid & 63, wv = tid >> 6;
  #pragma unroll
  for (int s = 0; s < NSP; ++s){
    unsigned long long m = __ballot(sv == s);
    if (lane == 0) wc[wv][s] = (int)__popcll(m);
  }
  __syncthreads();
  if (tid < NSP)
    hist[tid*nb + blk] = wc[0][tid] + wc[1][tid] + wc[2][tid] + wc[3][tid];
}

// Pass 2: exclusive scan over 4*nb counters (species-major) -> base[], segOff[5].
// Single block, 1024 threads, 16 items/thread (covers nb <= 4096).
__global__ __launch_bounds__(1024) void scan_k2(const int* __restrict__ hist, int nb,
                                                int* __restrict__ base, int* __restrict__ segOff){
  int total = NSP*nb;
  int tid = threadIdx.x;
  int g0 = tid*16;
  int v[16]; int s = 0;
  #pragma unroll
  for (int i = 0; i < 16; ++i){
    int g = g0 + i;
    int x = (g < total) ? hist[g] : 0;
    v[i] = s; s += x;                      // v[i] = exclusive within thread
  }
  int lane = tid & 63, wv = tid >> 6;
  int incl = s;
  #pragma unroll
  for (int off = 1; off < 64; off <<= 1){
    int t = __shfl_up(incl, off, 64);
    if (lane >= off) incl += t;
  }
  __shared__ int wsum[16];
  if (lane == 63) wsum[wv] = incl;
  __syncthreads();
  int wbase = 0;
  #pragma unroll
  for (int w = 0; w < 16; ++w) wbase += (w < wv) ? wsum[w] : 0;
  int exclT = wbase + incl - s;
  #pragma unroll
  for (int i = 0; i < 16; ++i){
    int g = g0 + i;
    int e = exclT + v[i];
    if (g < total) base[g] = e;
    if (g <= total && (g % nb) == 0) segOff[g / nb] = e;   // g==total -> segOff[4]=n
  }
}

// Pass 3: stable scatter — rank within block via ballots + cross-wave LDS prefix.
__global__ void scatter_k2(const int* __restrict__ sp, int n, int nb,
                           const int* __restrict__ base, int* __restrict__ sorted){
  int blk = blockIdx.x, tid = threadIdx.x;
  int i = blk*256 + tid;
  int sv = (i < n) ? sp[i] : -1;
  __shared__ int cnt[4][NSP];
  __shared__ int wb[4][NSP];
  __shared__ int hb[NSP];
  int lane = tid & 63, wv = tid >> 6;
  unsigned long long msel = 0;
  #pragma unroll
  for (int s = 0; s < NSP; ++s){
    unsigned long long m = __ballot(sv == s);
    if (lane == 0) cnt[wv][s] = (int)__popcll(m);
    if (sv == s) msel = m;
  }
  if (tid < NSP) hb[tid] = base[tid*nb + blk];
  __syncthreads();
  if (tid < 16){
    int w = tid >> 2, s = tid & 3;
    int b = hb[s];
    if (w > 0) b += cnt[0][s];
    if (w > 1) b += cnt[1][s];
    if (w > 2) b += cnt[2][s];
    wb[w][s] = b;
  }
  __syncthreads();
  if (sv >= 0){
    int rank = (int)__popcll(msel & ((1ull << lane) - 1ull));
    sorted[wb[wv][sv] + rank] = i;
  }
}

// ---------------- main MLP kernel (swapped-operand layout) ----------------
// MFMA computes D = W^T (A) @ X^T (B) so C holds [n][atom]:
//  - h1 transpose to LDS is 4x ds_write_b64 (was 16x ds_write_b16)
//  - final reduce is 2 shfl_xor across quads (was 4-level 16-lane tree)
//  - every lane knows its atom's gather row -> no rid bpermutes, stores from
//    lanes 0-15 over nearly-consecutive (stable-sorted) atom ids.

#define BPS 128   // blocks per species

__global__ __launch_bounds__(256, 2) void mlp3_k(
    const float* __restrict__ feats,
    const float* __restrict__ b1, const float* __restrict__ b2,
    const float* __restrict__ W3, const float* __restrict__ b3,
    const int* __restrict__ segOff, const int* __restrict__ sorted,
    const u16* __restrict__ w1t, const u16* __restrict__ w2t,
    float* __restrict__ out)
{
  __shared__ __align__(16) u16 sW1[64*136];        // 17,408 B
  __shared__ __align__(16) u16 sW2[64*72];         //  9,216 B
  __shared__ float sB1[64], sB2[64], sW3s[64];
  __shared__ __align__(16) u16 sH[4][16*72];       //  9,216 B (per-wave h1^T scratch)

  int s  = blockIdx.x >> 7;
  int bs = blockIdx.x & (BPS-1);
  int tid = threadIdx.x;
  int segB = segOff[s], segE = segOff[s+1];
  int cnt = segE - segB;
  int tiles = (cnt + 63) >> 6;

  { // stage this species' weights once (full coverage: 256 thr)
    int r = tid >> 2, q = tid & 3;
    const uint4* sp1 = (const uint4*)(w1t + (size_t)(s*64 + r)*128 + q*32);
    uint4 a0 = sp1[0], a1 = sp1[1], a2 = sp1[2], a3 = sp1[3];
    const uint4* sp2 = (const uint4*)(w2t + (size_t)(s*64 + r)*64 + q*16);
    uint4 c0 = sp2[0], c1 = sp2[1];
    uint4* d1 = (uint4*)(sW1 + r*136 + q*32);
    d1[0]=a0; d1[1]=a1; d1[2]=a2; d1[3]=a3;
    uint4* d2 = (uint4*)(sW2 + r*72 + q*16);
    d2[0]=c0; d2[1]=c1;
  }
  if (tid < 64)        sB1[tid]       = b1[s*64 + tid];
  else if (tid < 128)  sB2[tid-64]    = b2[s*64 + tid-64];
  else if (tid < 192)  sW3s[tid-128]  = W3[s*64 + tid-128];
  __syncthreads();

  int lane = tid & 63, wv = tid >> 6;
  int cc = lane & 15, quad = lane >> 4;

  // A-side weight fragments (identical packing to before) + per-lane epilogue
  // constants, now indexed n = nt*16 + quad*4 + r (C-row layout).
  v8bf bw1[4][4], bw2[4][2];
  float b1c[4][4], b2c[4][4], w3c[4][4];
  #pragma unroll
  for (int nt = 0; nt < 4; ++nt){
    #pragma unroll
    for (int kk = 0; kk < 4; ++kk)
      bw1[nt][kk] = *(const v8bf*)(sW1 + (nt*16+cc)*136 + kk*32 + quad*8);
    #pragma unroll
    for (int kk = 0; kk < 2; ++kk)
      bw2[nt][kk] = *(const v8bf*)(sW2 + (nt*16+cc)*72 + kk*32 + quad*8);
    #pragma unroll
    for (int r = 0; r < 4; ++r){
      b1c[nt][r] = sB1[nt*16 + quad*4 + r];
      b2c[nt][r] = sB2[nt*16 + quad*4 + r];
      w3c[nt][r] = sW3s[nt*16 + quad*4 + r];
    }
  }
  float b3v = b3[s];
  u16* myH = (u16*)sH[wv];

  // contiguous chunk per block (stable sort => streaming gather + local stores)
  int per = (tiles + BPS - 1) >> 7;
  int tBeg = bs * per;
  int tEnd = min(tiles, tBeg + per);
  if (tBeg >= tEnd) return;

  auto idxLoad = [&](int t) -> int {
    int tc = t < tEnd-1 ? t : tEnd-1;          // clamp prefetch inside own chunk
    int p = segB + tc*64 + wv*16 + cc;
    if (p > segE-1) p = segE-1;
    return sorted[p];
  };
  auto featLoad = [&](int ri, float4 (&f)[8]){
    const float4* fp = (const float4*)(feats + (size_t)ri*128 + quad*8);
    #pragma unroll
    for (int kk = 0; kk < 4; ++kk){ f[kk*2] = fp[kk*8]; f[kk*2+1] = fp[kk*8+1]; }
  };
  auto packA = [&](const float4 (&f)[8], unsigned (&P)[4][4]){
    #pragma unroll
    for (int kk = 0; kk < 4; ++kk){
      P[kk][0] = pack2bf(f[kk*2].x,   f[kk*2].y);
      P[kk][1] = pack2bf(f[kk*2].z,   f[kk*2].w);
      P[kk][2] = pack2bf(f[kk*2+1].x, f[kk*2+1].y);
      P[kk][3] = pack2bf(f[kk*2+1].z, f[kk*2+1].w);
    }
  };

  auto compute = [&](int t, const unsigned (&P)[4][4], int ri){
    // layer 1: acc[nt] holds h1^T[n = nt*16+quad*4+r][atom = cc]
    v4f acc[4];
    #pragma unroll
    for (int nt = 0; nt < 4; ++nt) acc[nt] = (v4f){0.f,0.f,0.f,0.f};
    #pragma unroll
    for (int kk = 0; kk < 4; ++kk){
      union { v8bf v; unsigned u[4]; } B;
      B.u[0] = P[kk][0]; B.u[1] = P[kk][1]; B.u[2] = P[kk][2]; B.u[3] = P[kk][3];
      #pragma unroll
      for (int nt = 0; nt < 4; ++nt)
        acc[nt] = __builtin_amdgcn_mfma_f32_16x16x32_bf16(bw1[nt][kk], B.v, acc[nt], 0, 0, 0);
    }
    // h1^T -> per-wave LDS, linear [atom][n], packed b64 per nt
    #pragma unroll
    for (int nt = 0; nt < 4; ++nt){
      float t0 = fast_tanh(acc[nt][0] + b1c[nt][0]);
      float t1 = fast_tanh(acc[nt][1] + b1c[nt][1]);
      float t2 = fast_tanh(acc[nt][2] + b1c[nt][2]);
      float t3 = fast_tanh(acc[nt][3] + b1c[nt][3]);
      uint2 w; w.x = pack2bf(t0, t1); w.y = pack2bf(t2, t3);
      *(uint2*)(myH + cc*72 + nt*16 + quad*4) = w;
    }
    // layer 2 B-frags (intra-wave LDS dep; compiler emits lgkmcnt wait)
    v8bf hB0 = *(const v8bf*)(myH + cc*72 +  0 + quad*8);
    v8bf hB1 = *(const v8bf*)(myH + cc*72 + 32 + quad*8);
    float e = 0.f;
    #pragma unroll
    for (int nt = 0; nt < 4; ++nt){
      v4f a2 = (v4f){0.f,0.f,0.f,0.f};
      a2 = __builtin_amdgcn_mfma_f32_16x16x32_bf16(bw2[nt][0], hB0, a2, 0, 0, 0);
      a2 = __builtin_amdgcn_mfma_f32_16x16x32_bf16(bw2[nt][1], hB1, a2, 0, 0, 0);
      #pragma unroll
      for (int r = 0; r < 4; ++r)
        e += fast_tanh(a2[r] + b2c[nt][r]) * w3c[nt][r];
    }
    // cross-quad reduce: full energy for atom cc in every lane
    e += __shfl_xor(e, 16, 64);
    e += __shfl_xor(e, 32, 64);
    if (quad == 0){
      int ap = t*64 + wv*16 + cc;
      if (ap < cnt) out[ri] = e + b3v;
    }
  };

  // 2-deep software pipeline: idx 2 tiles ahead, feats 1 tile ahead,
  // bf16 conversion after compute (vmcnt wait lands post-compute).
  int riA = idxLoad(tBeg);
  int riB = idxLoad(tBeg + 1);
  float4 fR[8];
  unsigned PA[4][4];
  featLoad(riA, fR);
  packA(fR, PA);
  for (int t = tBeg; t < tEnd; ++t){
    int riC = idxLoad(t + 2);
    featLoad(riB, fR);
    compute(t, PA, riA);
    packA(fR, PA);
    riA = riB; riB = riC;
  }
}

extern "C" void kernel_launch(void* const* d_in, const int* in_sizes, int n_in,
                              void* d_out, int out_size, void* d_ws, size_t ws_size,
                              hipStream_t stream){
  const float* feats  = (const float*)d_in[0];
  const int*   species= (const int*)d_in[1];
  const float* W1 = (const float*)d_in[2];
  const float* b1 = (const float*)d_in[3];
  const float* W2 = (const float*)d_in[4];
  const float* b2 = (const float*)d_in[5];
  const float* W3 = (const float*)d_in[6];
  const float* b3 = (const float*)d_in[7];
  float* out = (float*)d_out;
  int n = in_sizes[1];
  int nb = (n + 255) / 256;

  char* ws = (char*)d_ws;
  size_t histB = ((size_t)NSP*nb*4 + 15) & ~(size_t)15;
  int* hist   = (int*)ws;                         // 4*nb ints
  int* base   = (int*)(ws + histB);               // 4*nb ints
  int* segOff = (int*)(ws + 2*histB);             // 5 ints
  int* sorted = (int*)(ws + 2*histB + 32);        // n ints
  size_t sortedB = ((size_t)n*4 + 15) & ~(size_t)15;
  u16* w1t = (u16*)(ws + 2*histB + 32 + sortedB); // 4*64*128 bf16
  u16* w2t = w1t + NSP*64*128;                    // 4*64*64 bf16

  histwconv_k<<<nb + 128, 256, 0, stream>>>(species, n, nb, hist, W1, W2, w1t, w2t);
  scan_k2<<<1, 1024, 0, stream>>>(hist, nb, base, segOff);
  scatter_k2<<<nb, 256, 0, stream>>>(species, n, nb, base, sorted);
  mlp3_k<<<NSP*BPS, 256, 0, stream>>>(feats, b1, b2, W3, b3, segOff, sorted, w1t, w2t, out);
}